// Round 13
// baseline (411.881 us; speedup 1.0000x reference)
//
#include <hip/hip_runtime.h>
#include <hip/hip_bf16.h>

// Tucker: out[a,s,t] = sum_{f,e,g} act[a,f]*state[s,e]*core[f,e,g]*state[t,g]
// A=64, S=T=1024, E=G=64, F=32.
//
// R12 = ABLATION ROUND. R9(6-deep x 24w) == R11(10-deep x 16w) == ~66us:
// outstanding-store product saturated; gemm ~57us @4.7TB/s vs 39us floor.
// Question: is the pace set by (a) the load+store pipeline alone, or (b) the
// MFMA->store dependency chain? Two dispatches, rep-inflated past the ~160us
// harness fills so each gets its own counter row:
//   gemm<5,0>: loads+stores, NO MFMA (stores preamble constant, asm keepalive
//              on loads) -> garbage, then
//   gemm<4,1>: full R11 compute x4 -> overwrites, correct final output.
// Compare per-rep A=dur1/5 vs F=dur2/4. A~F -> memory ceiling; A<<F -> chain.

typedef __attribute__((ext_vector_type(8))) __bf16 bf16x8;
typedef __attribute__((ext_vector_type(4))) float f32x4;

static __device__ __forceinline__ unsigned short f2bf(float x) {
    union { float f; unsigned int u; } c; c.f = x;
    unsigned int lsb = (c.u >> 16) & 1u;
    c.u += 0x7fffu + lsb;               // round-to-nearest-even
    return (unsigned short)(c.u >> 16);
}

// ---- prep: fused state->bf16 conversion + Wt build (unchanged) ----
__global__ __launch_bounds__(256) void prep(const float* __restrict__ state,
                                            const float* __restrict__ act,
                                            const float* __restrict__ core,
                                            unsigned short* __restrict__ sb,
                                            unsigned short* __restrict__ wt) {
    int bx = blockIdx.x;          // 256 blocks: a(64) x chunk(4)
    int a = bx >> 2, ch = bx & 3;
    int t = threadIdx.x;
    {   // state cvt: 16384 float4s, 64 per block (threads 0..63)
        if (t < 64) {
            int i = bx * 64 + t;
            float4 v = reinterpret_cast<const float4*>(state)[i];
            union { unsigned short u[4]; unsigned long long ull; } r;
            r.u[0] = f2bf(v.x); r.u[1] = f2bf(v.y); r.u[2] = f2bf(v.z); r.u[3] = f2bf(v.w);
            reinterpret_cast<unsigned long long*>(sb)[i] = r.ull;
        }
    }
    __shared__ float af[32];
    if (t < 32) af[t] = act[a * 32 + t];
    __syncthreads();
#pragma unroll
    for (int i = 0; i < 4; ++i) {
        int idx = ch * 1024 + i * 256 + t;   // 1024 (e,g) pairs per block
        int e = idx >> 6, g = idx & 63;
        float acc = 0.f;
#pragma unroll
        for (int f = 0; f < 32; ++f)
            acc += af[f] * core[(f * 64 + e) * 64 + g];
        wt[a * 4096 + g * 64 + e] = f2bf(acc);   // store transposed (g,e)
    }
}

// ---- gemm: R11 structure; REPS internal repetitions; FULL=0 drops MFMA ----
template<int REPS, int FULL>
__global__ __launch_bounds__(256, 4) void gemm(const unsigned short* __restrict__ sb,
                                               const unsigned short* __restrict__ wt,
                                               float* __restrict__ out) {
    __shared__ unsigned short uls[32 * 72];   // U tile, pitch 72 bf16 (4608 B)

    int bx = blockIdx.x;                  // 2048 blocks
    int rb = (bx & 7) * 256 + (bx >> 3);  // XCD-chunked, bijective (2048 = 8*256)
    int wid = threadIdx.x >> 6, lane = threadIdx.x & 63;
    int lr = lane & 15, lk = (lane >> 4) * 8;
    int rr = (lane >> 4) * 4;
    size_t R0 = (size_t)rb * 32;          // first out row (flat (a,s))
    int a = rb >> 5;                      // 32 blocks per a
    int sloc = (rb & 31) * 32;            // s-within-a of first row

    // ---- preamble: U[s][g], s in [0,32), g in [0,64); also yields cval for FULL=0 ----
    f32x4 cval = {};
    {
        const unsigned short* wta = wt + a * 4096;
        int sh = wid & 1, gh = wid >> 1;
        bf16x8 bs0 = *reinterpret_cast<const bf16x8*>(sb + (sloc + sh * 16 + lr) * 64 + lk);
        bf16x8 bs1 = *reinterpret_cast<const bf16x8*>(sb + (sloc + sh * 16 + lr) * 64 + 32 + lk);
#pragma unroll
        for (int gg = 0; gg < 2; ++gg) {
            bf16x8 ag0 = *reinterpret_cast<const bf16x8*>(wta + (gh * 32 + gg * 16 + lr) * 64 + lk);
            bf16x8 ag1 = *reinterpret_cast<const bf16x8*>(wta + (gh * 32 + gg * 16 + lr) * 64 + 32 + lk);
            f32x4 uacc = {};
            uacc = __builtin_amdgcn_mfma_f32_16x16x32_bf16(ag0, bs0, uacc, 0, 0, 0);
            uacc = __builtin_amdgcn_mfma_f32_16x16x32_bf16(ag1, bs1, uacc, 0, 0, 0);
            union { unsigned short h[4]; unsigned long long ull; } pk;
#pragma unroll
            for (int q = 0; q < 4; ++q) pk.h[q] = f2bf(uacc[q]);
            *reinterpret_cast<unsigned long long*>(uls + (sh * 16 + lr) * 72 + gh * 32 + gg * 16 + rr) = pk.ull;
            cval = uacc;
        }
    }
    __syncthreads();

    // B-frags: U-local rows rg*16+lr (read once from LDS)
    bf16x8 bU0[2], bU1[2];
#pragma unroll
    for (int rg = 0; rg < 2; ++rg) {
        bU0[rg] = *reinterpret_cast<const bf16x8*>(uls + (rg * 16 + lr) * 72 + lk);
        bU1[rg] = *reinterpret_cast<const bf16x8*>(uls + (rg * 16 + lr) * 72 + 32 + lk);
    }

    // ---- t-sweep: wave w covers t in [w*256, w*256+256) for all 32 rows ----
    int t0w = wid * 256;
    float* ob0 = out + (R0 + lr) * 1024 + rr;        // rows R0..R0+15
    float* ob1 = out + (R0 + 16 + lr) * 1024 + rr;   // rows R0+16..R0+31

    for (int rep = 0; rep < REPS; ++rep) {
        asm volatile("" ::: "memory");    // keep reps distinct
#pragma unroll 16
        for (int mm = 0; mm < 16; ++mm) {
            int t0 = t0w + mm * 16;
            bf16x8 a0 = *reinterpret_cast<const bf16x8*>(sb + (t0 + lr) * 64 + lk);
            bf16x8 a1 = *reinterpret_cast<const bf16x8*>(sb + (t0 + lr) * 64 + 32 + lk);
            if (FULL) {
                f32x4 acc0 = {}, acc1 = {};
                acc0 = __builtin_amdgcn_mfma_f32_16x16x32_bf16(a0, bU0[0], acc0, 0, 0, 0);
                acc0 = __builtin_amdgcn_mfma_f32_16x16x32_bf16(a1, bU1[0], acc0, 0, 0, 0);
                acc1 = __builtin_amdgcn_mfma_f32_16x16x32_bf16(a0, bU0[1], acc1, 0, 0, 0);
                acc1 = __builtin_amdgcn_mfma_f32_16x16x32_bf16(a1, bU1[1], acc1, 0, 0, 0);
                *reinterpret_cast<f32x4*>(ob0 + t0) = acc0;
                *reinterpret_cast<f32x4*>(ob1 + t0) = acc1;
            } else {
                asm volatile("" :: "v"(a0), "v"(a1));   // keep loads (no DCE)
                *reinterpret_cast<f32x4*>(ob0 + t0) = cval;
                *reinterpret_cast<f32x4*>(ob1 + t0) = cval;
            }
        }
    }
}

extern "C" void kernel_launch(void* const* d_in, const int* in_sizes, int n_in,
                              void* d_out, int out_size, void* d_ws, size_t ws_size,
                              hipStream_t stream) {
    const float* state = (const float*)d_in[0];   // 1024 x 64
    const float* act   = (const float*)d_in[1];   // 64 x 32
    const float* core  = (const float*)d_in[2];   // 32 x 64 x 64
    float* out = (float*)d_out;                   // 64 x 1024 x 1024

    unsigned short* sb = (unsigned short*)d_ws;   // state bf16: 65536 (128 KB)
    unsigned short* wt = sb + 65536;              // Wt bf16:   262144 (512 KB)

    prep<<<256, 256, 0, stream>>>(state, act, core, sb, wt);
    gemm<5, 0><<<2048, 256, 0, stream>>>(sb, wt, out);   // ablated: loads+stores only
    gemm<4, 1><<<2048, 256, 0, stream>>>(sb, wt, out);   // full: correct overwrite
}

// Round 14
// 96.211 us; speedup vs baseline: 4.2810x; 4.2810x over previous
//
#include <hip/hip_runtime.h>
#include <hip/hip_bf16.h>

// Tucker: out[a,s,t] = sum_{f,e,g} act[a,f]*state[s,e]*core[f,e,g]*state[t,g]
// A=64, S=T=1024, E=G=64, F=32.
//
// R13 = R11 + NONTEMPORAL out stores (single variable A/B).
// R12 ablation: no-MFMA == full == ~43-45us/rep steady @~6 TB/s (write
// roofline); single-pass runs ~58us due to a COLD-PASS transient (~15us).
// Only kernel-addressable mechanism: L2 write-allocate churn (out has zero
// reuse; poison fill leaves dirty L2). NT stores skip L2 allocation.
//  prep: state->bf16 (sb) + Wt[a][g][e]=sum_f act*core (bf16)  [unchanged]
//  gemm: R11 structure exactly (2048 blocks x 32 rows, (256,4), unroll 16,
//        dual accumulator chain), stores via __builtin_nontemporal_store.

typedef __attribute__((ext_vector_type(8))) __bf16 bf16x8;
typedef __attribute__((ext_vector_type(4))) float f32x4;

static __device__ __forceinline__ unsigned short f2bf(float x) {
    union { float f; unsigned int u; } c; c.f = x;
    unsigned int lsb = (c.u >> 16) & 1u;
    c.u += 0x7fffu + lsb;               // round-to-nearest-even
    return (unsigned short)(c.u >> 16);
}

// ---- prep: fused state->bf16 conversion + Wt build (unchanged) ----
__global__ __launch_bounds__(256) void prep(const float* __restrict__ state,
                                            const float* __restrict__ act,
                                            const float* __restrict__ core,
                                            unsigned short* __restrict__ sb,
                                            unsigned short* __restrict__ wt) {
    int bx = blockIdx.x;          // 256 blocks: a(64) x chunk(4)
    int a = bx >> 2, ch = bx & 3;
    int t = threadIdx.x;
    {   // state cvt: 16384 float4s, 64 per block (threads 0..63)
        if (t < 64) {
            int i = bx * 64 + t;
            float4 v = reinterpret_cast<const float4*>(state)[i];
            union { unsigned short u[4]; unsigned long long ull; } r;
            r.u[0] = f2bf(v.x); r.u[1] = f2bf(v.y); r.u[2] = f2bf(v.z); r.u[3] = f2bf(v.w);
            reinterpret_cast<unsigned long long*>(sb)[i] = r.ull;
        }
    }
    __shared__ float af[32];
    if (t < 32) af[t] = act[a * 32 + t];
    __syncthreads();
#pragma unroll
    for (int i = 0; i < 4; ++i) {
        int idx = ch * 1024 + i * 256 + t;   // 1024 (e,g) pairs per block
        int e = idx >> 6, g = idx & 63;
        float acc = 0.f;
#pragma unroll
        for (int f = 0; f < 32; ++f)
            acc += af[f] * core[(f * 64 + e) * 64 + g];
        wt[a * 4096 + g * 64 + e] = f2bf(acc);   // store transposed (g,e)
    }
}

// ---- gemm: R11 structure + nontemporal stores ----
__global__ __launch_bounds__(256, 4) void gemm(const unsigned short* __restrict__ sb,
                                               const unsigned short* __restrict__ wt,
                                               float* __restrict__ out) {
    __shared__ unsigned short uls[32 * 72];   // U tile, pitch 72 bf16 (4608 B)

    int bx = blockIdx.x;                  // 2048 blocks
    int rb = (bx & 7) * 256 + (bx >> 3);  // XCD-chunked, bijective (2048 = 8*256)
    int wid = threadIdx.x >> 6, lane = threadIdx.x & 63;
    int lr = lane & 15, lk = (lane >> 4) * 8;
    int rr = (lane >> 4) * 4;
    size_t R0 = (size_t)rb * 32;          // first out row (flat (a,s))
    int a = rb >> 5;                      // 32 blocks per a
    int sloc = (rb & 31) * 32;            // s-within-a of first row

    // ---- preamble: U[s][g] = sum_e sb[sloc+s][e]*wta[g][e], s in [0,32), g in [0,64)
    // wave w: s-half sh=w&1 (16 rows), g-half gh=w>>1 (32 g)
    {
        const unsigned short* wta = wt + a * 4096;
        int sh = wid & 1, gh = wid >> 1;
        bf16x8 bs0 = *reinterpret_cast<const bf16x8*>(sb + (sloc + sh * 16 + lr) * 64 + lk);
        bf16x8 bs1 = *reinterpret_cast<const bf16x8*>(sb + (sloc + sh * 16 + lr) * 64 + 32 + lk);
#pragma unroll
        for (int gg = 0; gg < 2; ++gg) {
            bf16x8 ag0 = *reinterpret_cast<const bf16x8*>(wta + (gh * 32 + gg * 16 + lr) * 64 + lk);
            bf16x8 ag1 = *reinterpret_cast<const bf16x8*>(wta + (gh * 32 + gg * 16 + lr) * 64 + 32 + lk);
            f32x4 uacc = {};
            uacc = __builtin_amdgcn_mfma_f32_16x16x32_bf16(ag0, bs0, uacc, 0, 0, 0);
            uacc = __builtin_amdgcn_mfma_f32_16x16x32_bf16(ag1, bs1, uacc, 0, 0, 0);
            // lane holds U[s = sh*16+lr][g = gh*32+gg*16+rr+q], q=0..3
            union { unsigned short h[4]; unsigned long long ull; } pk;
#pragma unroll
            for (int q = 0; q < 4; ++q) pk.h[q] = f2bf(uacc[q]);
            *reinterpret_cast<unsigned long long*>(uls + (sh * 16 + lr) * 72 + gh * 32 + gg * 16 + rr) = pk.ull;
        }
    }
    __syncthreads();

    // B-frags: U-local rows rg*16+lr (read once from LDS)
    bf16x8 bU0[2], bU1[2];
#pragma unroll
    for (int rg = 0; rg < 2; ++rg) {
        bU0[rg] = *reinterpret_cast<const bf16x8*>(uls + (rg * 16 + lr) * 72 + lk);
        bU1[rg] = *reinterpret_cast<const bf16x8*>(uls + (rg * 16 + lr) * 72 + 32 + lk);
    }

    // ---- t-sweep: wave w covers t in [w*256, w*256+256) for all 32 rows ----
    int t0w = wid * 256;
    float* ob0 = out + (R0 + lr) * 1024 + rr;        // rows R0..R0+15
    float* ob1 = out + (R0 + 16 + lr) * 1024 + rr;   // rows R0+16..R0+31

#pragma unroll 16
    for (int mm = 0; mm < 16; ++mm) {
        int t0 = t0w + mm * 16;
        bf16x8 a0 = *reinterpret_cast<const bf16x8*>(sb + (t0 + lr) * 64 + lk);
        bf16x8 a1 = *reinterpret_cast<const bf16x8*>(sb + (t0 + lr) * 64 + 32 + lk);
        f32x4 acc0 = {}, acc1 = {};
        acc0 = __builtin_amdgcn_mfma_f32_16x16x32_bf16(a0, bU0[0], acc0, 0, 0, 0);
        acc0 = __builtin_amdgcn_mfma_f32_16x16x32_bf16(a1, bU1[0], acc0, 0, 0, 0);
        acc1 = __builtin_amdgcn_mfma_f32_16x16x32_bf16(a0, bU0[1], acc1, 0, 0, 0);
        acc1 = __builtin_amdgcn_mfma_f32_16x16x32_bf16(a1, bU1[1], acc1, 0, 0, 0);
        // lane: out[R0 + rg*16 + lr][t0 + rr + q] -> one 16B NT store per chain
        __builtin_nontemporal_store(acc0, reinterpret_cast<f32x4*>(ob0 + t0));
        __builtin_nontemporal_store(acc1, reinterpret_cast<f32x4*>(ob1 + t0));
    }
}

extern "C" void kernel_launch(void* const* d_in, const int* in_sizes, int n_in,
                              void* d_out, int out_size, void* d_ws, size_t ws_size,
                              hipStream_t stream) {
    const float* state = (const float*)d_in[0];   // 1024 x 64
    const float* act   = (const float*)d_in[1];   // 64 x 32
    const float* core  = (const float*)d_in[2];   // 32 x 64 x 64
    float* out = (float*)d_out;                   // 64 x 1024 x 1024

    unsigned short* sb = (unsigned short*)d_ws;   // state bf16: 65536 (128 KB)
    unsigned short* wt = sb + 65536;              // Wt bf16:   262144 (512 KB)

    prep<<<256, 256, 0, stream>>>(state, act, core, sb, wt);
    gemm<<<2048, 256, 0, stream>>>(sb, wt, out);
}

// Round 15
// 65.824 us; speedup vs baseline: 6.2573x; 1.4616x over previous
//
#include <hip/hip_runtime.h>
#include <hip/hip_bf16.h>

// Tucker: out[a,s,t] = sum_{f,e,g} act[a,f]*state[s,e]*core[f,e,g]*state[t,g]
// A=64, S=T=1024, E=G=64, F=32.
//
// R14 = REVERT to R11 (best verified, 65.8us). R13's NT-store A/B regressed
// to 96us, proving L2 allocate-on-miss is the write-combiner for our 64B
// fragment segments -- the final open theory for the ~15us cold-pass
// transient is falsified. R12 ablation showed this structure's steady write
// rate equals the fill kernel's ceiling (~43us/268MB); single-pass floor
// ~56-58us is bracketed by 6 falsified structural alternatives. This is the
// structure's measured floor.
//  prep: state->bf16 (sb) + Wt[a][g][e]=sum_f act*core (bf16)
//  gemm: 2048 blocks x 32 rows, (256,4), unroll-16 dual-chain t-sweep,
//        normal (L2-allocating) dwordx4 stores, XCD-chunked block mapping.

typedef __attribute__((ext_vector_type(8))) __bf16 bf16x8;
typedef __attribute__((ext_vector_type(4))) float f32x4;

static __device__ __forceinline__ unsigned short f2bf(float x) {
    union { float f; unsigned int u; } c; c.f = x;
    unsigned int lsb = (c.u >> 16) & 1u;
    c.u += 0x7fffu + lsb;               // round-to-nearest-even
    return (unsigned short)(c.u >> 16);
}

// ---- prep: fused state->bf16 conversion + Wt build ----
__global__ __launch_bounds__(256) void prep(const float* __restrict__ state,
                                            const float* __restrict__ act,
                                            const float* __restrict__ core,
                                            unsigned short* __restrict__ sb,
                                            unsigned short* __restrict__ wt) {
    int bx = blockIdx.x;          // 256 blocks: a(64) x chunk(4)
    int a = bx >> 2, ch = bx & 3;
    int t = threadIdx.x;
    {   // state cvt: 16384 float4s, 64 per block (threads 0..63)
        if (t < 64) {
            int i = bx * 64 + t;
            float4 v = reinterpret_cast<const float4*>(state)[i];
            union { unsigned short u[4]; unsigned long long ull; } r;
            r.u[0] = f2bf(v.x); r.u[1] = f2bf(v.y); r.u[2] = f2bf(v.z); r.u[3] = f2bf(v.w);
            reinterpret_cast<unsigned long long*>(sb)[i] = r.ull;
        }
    }
    __shared__ float af[32];
    if (t < 32) af[t] = act[a * 32 + t];
    __syncthreads();
#pragma unroll
    for (int i = 0; i < 4; ++i) {
        int idx = ch * 1024 + i * 256 + t;   // 1024 (e,g) pairs per block
        int e = idx >> 6, g = idx & 63;
        float acc = 0.f;
#pragma unroll
        for (int f = 0; f < 32; ++f)
            acc += af[f] * core[(f * 64 + e) * 64 + g];
        wt[a * 4096 + g * 64 + e] = f2bf(acc);   // store transposed (g,e)
    }
}

// ---- gemm: 2048 blocks x 32 rows; deep-pipelined t-quarter sweep ----
__global__ __launch_bounds__(256, 4) void gemm(const unsigned short* __restrict__ sb,
                                               const unsigned short* __restrict__ wt,
                                               float* __restrict__ out) {
    __shared__ unsigned short uls[32 * 72];   // U tile, pitch 72 bf16 (4608 B)

    int bx = blockIdx.x;                  // 2048 blocks
    int rb = (bx & 7) * 256 + (bx >> 3);  // XCD-chunked, bijective (2048 = 8*256)
    int wid = threadIdx.x >> 6, lane = threadIdx.x & 63;
    int lr = lane & 15, lk = (lane >> 4) * 8;
    int rr = (lane >> 4) * 4;
    size_t R0 = (size_t)rb * 32;          // first out row (flat (a,s))
    int a = rb >> 5;                      // 32 blocks per a
    int sloc = (rb & 31) * 32;            // s-within-a of first row

    // ---- preamble: U[s][g] = sum_e sb[sloc+s][e]*wta[g][e], s in [0,32), g in [0,64)
    // wave w: s-half sh=w&1 (16 rows), g-half gh=w>>1 (32 g)
    {
        const unsigned short* wta = wt + a * 4096;
        int sh = wid & 1, gh = wid >> 1;
        bf16x8 bs0 = *reinterpret_cast<const bf16x8*>(sb + (sloc + sh * 16 + lr) * 64 + lk);
        bf16x8 bs1 = *reinterpret_cast<const bf16x8*>(sb + (sloc + sh * 16 + lr) * 64 + 32 + lk);
#pragma unroll
        for (int gg = 0; gg < 2; ++gg) {
            bf16x8 ag0 = *reinterpret_cast<const bf16x8*>(wta + (gh * 32 + gg * 16 + lr) * 64 + lk);
            bf16x8 ag1 = *reinterpret_cast<const bf16x8*>(wta + (gh * 32 + gg * 16 + lr) * 64 + 32 + lk);
            f32x4 uacc = {};
            uacc = __builtin_amdgcn_mfma_f32_16x16x32_bf16(ag0, bs0, uacc, 0, 0, 0);
            uacc = __builtin_amdgcn_mfma_f32_16x16x32_bf16(ag1, bs1, uacc, 0, 0, 0);
            // lane holds U[s = sh*16+lr][g = gh*32+gg*16+rr+q], q=0..3
            union { unsigned short h[4]; unsigned long long ull; } pk;
#pragma unroll
            for (int q = 0; q < 4; ++q) pk.h[q] = f2bf(uacc[q]);
            *reinterpret_cast<unsigned long long*>(uls + (sh * 16 + lr) * 72 + gh * 32 + gg * 16 + rr) = pk.ull;
        }
    }
    __syncthreads();

    // B-frags: U-local rows rg*16+lr (read once from LDS)
    bf16x8 bU0[2], bU1[2];
#pragma unroll
    for (int rg = 0; rg < 2; ++rg) {
        bU0[rg] = *reinterpret_cast<const bf16x8*>(uls + (rg * 16 + lr) * 72 + lk);
        bU1[rg] = *reinterpret_cast<const bf16x8*>(uls + (rg * 16 + lr) * 72 + 32 + lk);
    }

    // ---- t-sweep: wave w covers t in [w*256, w*256+256) for all 32 rows ----
    int t0w = wid * 256;
    float* ob0 = out + (R0 + lr) * 1024 + rr;        // rows R0..R0+15
    float* ob1 = out + (R0 + 16 + lr) * 1024 + rr;   // rows R0+16..R0+31

#pragma unroll 16
    for (int mm = 0; mm < 16; ++mm) {
        int t0 = t0w + mm * 16;
        bf16x8 a0 = *reinterpret_cast<const bf16x8*>(sb + (t0 + lr) * 64 + lk);
        bf16x8 a1 = *reinterpret_cast<const bf16x8*>(sb + (t0 + lr) * 64 + 32 + lk);
        f32x4 acc0 = {}, acc1 = {};
        acc0 = __builtin_amdgcn_mfma_f32_16x16x32_bf16(a0, bU0[0], acc0, 0, 0, 0);
        acc0 = __builtin_amdgcn_mfma_f32_16x16x32_bf16(a1, bU1[0], acc0, 0, 0, 0);
        acc1 = __builtin_amdgcn_mfma_f32_16x16x32_bf16(a0, bU0[1], acc1, 0, 0, 0);
        acc1 = __builtin_amdgcn_mfma_f32_16x16x32_bf16(a1, bU1[1], acc1, 0, 0, 0);
        // lane: out[R0 + rg*16 + lr][t0 + rr + q] -> one 16B store per chain
        *reinterpret_cast<f32x4*>(ob0 + t0) = acc0;
        *reinterpret_cast<f32x4*>(ob1 + t0) = acc1;
    }
}

extern "C" void kernel_launch(void* const* d_in, const int* in_sizes, int n_in,
                              void* d_out, int out_size, void* d_ws, size_t ws_size,
                              hipStream_t stream) {
    const float* state = (const float*)d_in[0];   // 1024 x 64
    const float* act   = (const float*)d_in[1];   // 64 x 32
    const float* core  = (const float*)d_in[2];   // 32 x 64 x 64
    float* out = (float*)d_out;                   // 64 x 1024 x 1024

    unsigned short* sb = (unsigned short*)d_ws;   // state bf16: 65536 (128 KB)
    unsigned short* wt = sb + 65536;              // Wt bf16:   262144 (512 KB)

    prep<<<256, 256, 0, stream>>>(state, act, core, sb, wt);
    gemm<<<2048, 256, 0, stream>>>(sb, wt, out);
}